// Round 10
// baseline (10703.416 us; speedup 1.0000x reference)
//
#include <hip/hip_runtime.h>

#define NVARS    12000
#define NNODES   8400
#define NLEAF    3600
#define NROUNDS  12
#define RPB      24              // rows per block
#define NB       500             // 500*24 = 12000; node boundary = 350*24 = 8400
#define NODE_BLKS 350
#define CAP      64
#define TPB      256             // 4 waves; 2 blocks/CU -> 8 waves/CU
#define NTH      (NB * TPB)

typedef _Float16 f16;
typedef _Float16 half8 __attribute__((ext_vector_type(8)));
typedef _Float16 half4v __attribute__((ext_vector_type(4)));
typedef float f32x4 __attribute__((ext_vector_type(4)));

#define MROW 136                 // LDS plane row stride (halves); 272 B
#define PROWS 32                 // plane height (24 real rows + 8 pad for the 16-row MFMA tile)
#define PLANE (PROWS * MROW)     // 4352 halves = 8704 B; 6 planes = 52224 B -> 2 blocks/CU

struct Params {
    float *t1a, *t1b;
    int *bar;
    const int *vt;
    int *ncnt, *nidx, *vcnt, *vidx;
    const unsigned int *unpack;        // fp32 bits of incidence matrix
    const float *true_w, *true_b, *false_w, *false_b;
    const float *wsrc[8];              // 8 MLP weight mats (fp32, [128][128])
    const float *vu_wih, *vu_whh, *nu_wih, *nu_whh;
    f16 *wm_hi, *wm_lo;                // 8 * 16384, [n][k]
    f16 *vu_hi, *vu_lo, *nu_hi, *nu_lo;// [512][256] (k<128: wih, k>=128: whh)
    const float *cm_b1, *cm_b2, *cm_b3, *pm_b1, *pm_b2, *pm_b3;
    const float *vv_b1, *vv_b2, *vv_w3, *vv_b3;
    const float *vu_bih, *vu_bhh, *nu_bih, *nu_bhh;
    float *out;
};

__device__ __forceinline__ float sigm(float x) { return 1.f / (1.f + expf(-x)); }

// ---- software grid barrier: all NB blocks co-resident (2 blocks/CU by LDS/VGPR)
__device__ __forceinline__ void gsync(int* bar, int target) {
    __syncthreads();
    __threadfence();
    if (threadIdx.x == 0) {
        atomicAdd(bar, 1);
        while (__hip_atomic_load(bar, __ATOMIC_ACQUIRE, __HIP_MEMORY_SCOPE_AGENT) < target)
            __builtin_amdgcn_s_sleep(2);
    }
    __syncthreads();
    __threadfence();
}

// near-fp32 split product: (Ah+Al)*(Bh+Bl) minus negligible Al*Bl
__device__ __forceinline__ f32x4 mfma3(half8 ah, half8 al, half8 bh, half8 bl, f32x4 acc) {
    acc = __builtin_amdgcn_mfma_f32_16x16x32_f16(ah, bh, acc, 0, 0, 0);
    acc = __builtin_amdgcn_mfma_f32_16x16x32_f16(al, bh, acc, 0, 0, 0);
    acc = __builtin_amdgcn_mfma_f32_16x16x32_f16(ah, bl, acc, 0, 0, 0);
    return acc;
}

// ---- one 128->128 MLP layer over the block's 24 rows; wave w owns cols [32w,32w+32)
// (rows 24..31 of the second MFMA tile are pad: computed but never stored to global)
__device__ void layerM(const f16* inHi, const f16* inLo,
                       const f16* Wh, const f16* Wl, const float* bias, bool relu,
                       f16* outHi, f16* outLo, float* gdst, int grow0) {
    const int lane = threadIdx.x & 63, l15 = lane & 15, quad = lane >> 4;
    const int w = threadIdx.x >> 6;          // 0..3
    half8 Bh[2][4], Bl[2][4];
#pragma unroll
    for (int ct = 0; ct < 2; ++ct)
#pragma unroll
        for (int s = 0; s < 4; ++s) {
            size_t off = (size_t)(w * 32 + ct * 16 + l15) * 128 + s * 32 + quad * 8;
            Bh[ct][s] = *(const half8*)(Wh + off);
            Bl[ct][s] = *(const half8*)(Wl + off);
        }
    float b0 = bias[w * 32 + l15], b1 = bias[w * 32 + 16 + l15];
#pragma unroll
    for (int mt = 0; mt < 2; ++mt) {
        half8 Ah[4], Al[4];
#pragma unroll
        for (int s = 0; s < 4; ++s) {
            int off = (mt * 16 + l15) * MROW + s * 32 + quad * 8;
            Ah[s] = *(const half8*)(inHi + off);
            Al[s] = *(const half8*)(inLo + off);
        }
        f32x4 acc0 = {0.f, 0.f, 0.f, 0.f}, acc1 = {0.f, 0.f, 0.f, 0.f};
#pragma unroll
        for (int s = 0; s < 4; ++s) {
            acc0 = mfma3(Ah[s], Al[s], Bh[0][s], Bl[0][s], acc0);
            acc1 = mfma3(Ah[s], Al[s], Bh[1][s], Bl[1][s], acc1);
        }
#pragma unroll
        for (int ct = 0; ct < 2; ++ct) {
            f32x4 a = ct ? acc1 : acc0;
            float bb = ct ? b1 : b0;
            int col = w * 32 + ct * 16 + l15;
#pragma unroll
            for (int reg = 0; reg < 4; ++reg) {
                int row = mt * 16 + quad * 4 + reg;
                float v = a[reg] + bb;
                if (relu) v = fmaxf(v, 0.f);
                if (gdst) {
                    if (row < RPB) gdst[(size_t)(grow0 + row) * 128 + col] = v;
                } else {
                    f16 hh = (f16)v;
                    outHi[row * MROW + col] = hh;       // pad rows harmless
                    outLo[row * MROW + col] = (f16)(v - (float)hh);
                }
            }
        }
    }
    __syncthreads();
}

// ---- LSTM over the block's 24 rows: A=[msg;h] K=256, 512 gate cols.
// Wave w owns cols w*32..w*32+31 within EACH gate; c-state in VGPRs; pointwise in-register.
__device__ void gatesL(const f16* msgHi, const f16* msgLo, f16* hHi, f16* hLo, float* cR,
                       const f16* Wh, const f16* Wl, const float* bih, const float* bhh) {
    const int lane = threadIdx.x & 63, l15 = lane & 15, quad = lane >> 4;
    const int w = threadIdx.x >> 6;
    float gb[4][2];
#pragma unroll
    for (int g = 0; g < 4; ++g)
#pragma unroll
        for (int c2 = 0; c2 < 2; ++c2) {
            int col = g * 128 + w * 32 + c2 * 16 + l15;
            gb[g][c2] = bih[col] + bhh[col];
        }
    f32x4 acc[2][4][2];
#pragma unroll
    for (int mt = 0; mt < 2; ++mt)
#pragma unroll
        for (int g = 0; g < 4; ++g)
#pragma unroll
            for (int c2 = 0; c2 < 2; ++c2)
                acc[mt][g][c2] = (f32x4){0.f, 0.f, 0.f, 0.f};

    for (int g = 0; g < 4; ++g) {
        half8 Bh[2][8], Bl[2][8];       // resident per gate (r7-proven structure)
#pragma unroll
        for (int c2 = 0; c2 < 2; ++c2)
#pragma unroll
            for (int s = 0; s < 8; ++s) {
                size_t off = (size_t)(g * 128 + w * 32 + c2 * 16 + l15) * 256 + s * 32 + quad * 8;
                Bh[c2][s] = *(const half8*)(Wh + off);
                Bl[c2][s] = *(const half8*)(Wl + off);
            }
#pragma unroll
        for (int mt = 0; mt < 2; ++mt) {
            half8 Ah[8], Al[8];
#pragma unroll
            for (int s = 0; s < 4; ++s) {
                int off = (mt * 16 + l15) * MROW + s * 32 + quad * 8;
                Ah[s]     = *(const half8*)(msgHi + off);
                Al[s]     = *(const half8*)(msgLo + off);
                Ah[s + 4] = *(const half8*)(hHi + off);
                Al[s + 4] = *(const half8*)(hLo + off);
            }
#pragma unroll
            for (int c2 = 0; c2 < 2; ++c2)
#pragma unroll
                for (int s = 0; s < 8; ++s)
                    acc[mt][g][c2] = mfma3(Ah[s], Al[s], Bh[c2][s], Bl[c2][s], acc[mt][g][c2]);
        }
    }
    __syncthreads();   // all h-plane reads done before pointwise rewrites h
#pragma unroll
    for (int mt = 0; mt < 2; ++mt)
#pragma unroll
        for (int c2 = 0; c2 < 2; ++c2) {
            int col = w * 32 + c2 * 16 + l15;
#pragma unroll
            for (int reg = 0; reg < 4; ++reg) {
                int row = mt * 16 + quad * 4 + reg;
                float gi = acc[mt][0][c2][reg] + gb[0][c2];
                float gf = acc[mt][1][c2][reg] + gb[1][c2];
                float gg = acc[mt][2][c2][reg] + gb[2][c2];
                float go = acc[mt][3][c2][reg] + gb[3][c2];
                float cv = cR[(mt * 2 + c2) * 4 + reg];
                float cn = sigm(gf) * cv + sigm(gi) * tanhf(gg);
                float hn = sigm(go) * tanhf(cn);
                cR[(mt * 2 + c2) * 4 + reg] = cn;
                f16 hh = (f16)hn;
                hHi[row * MROW + col] = hh;             // pad rows harmless
                hLo[row * MROW + col] = (f16)(hn - (float)hh);
            }
        }
    __syncthreads();
}

// ---- gather own 24 rows from global t1 into msg planes (hi/lo)
__device__ void gatherP(const float* t1g, const int* cnt, const int* idxm,
                        f16* msgHi, f16* msgLo, int R0) {
    if (threadIdx.x < 192) {
        int r = threadIdx.x >> 3, q = threadIdx.x & 7;   // 24 rows x 8 col-segments
        int row = R0 + r;
        int n = cnt[row]; if (n > CAP) n = CAP;
        const int* ir = idxm + (size_t)row * CAP;
        float a[16];
#pragma unroll
        for (int u = 0; u < 16; ++u) a[u] = 0.f;
        for (int j = 0; j < n; ++j) {
            const float4* s4 = (const float4*)(t1g + (size_t)ir[j] * 128) + q * 4;
#pragma unroll
            for (int u = 0; u < 4; ++u) {
                float4 v = s4[u];
                a[u * 4 + 0] += v.x; a[u * 4 + 1] += v.y;
                a[u * 4 + 2] += v.z; a[u * 4 + 3] += v.w;
            }
        }
#pragma unroll
        for (int u4 = 0; u4 < 4; ++u4) {
            half4v hh, ll;
#pragma unroll
            for (int k = 0; k < 4; ++k) {
                float x = a[u4 * 4 + k];
                f16 h = (f16)x;
                hh[k] = h; ll[k] = (f16)(x - (float)h);
            }
            int off = r * MROW + q * 16 + u4 * 4;
            *(half4v*)(msgHi + off) = hh;
            *(half4v*)(msgLo + off) = ll;
        }
    }
    __syncthreads();
}

// ---------------------------------------------------------------------------
__global__ void __launch_bounds__(TPB, 2) mega(Params p) {
    __shared__ __align__(16) f16 smh[6 * PLANE];   // 52.2 KB -> 2 blocks/CU
    f16 *hHi = smh,             *hLo = smh + PLANE;
    f16 *aHi = smh + 2 * PLANE, *aLo = smh + 3 * PLANE;
    f16 *bHi = smh + 4 * PLANE, *bLo = smh + 5 * PLANE;

    const int R0 = blockIdx.x * RPB;
    const bool isNode = blockIdx.x < NODE_BLKS;
    const int gtid = blockIdx.x * TPB + threadIdx.x;

    // ---- prologue: weight split-conversion + CSR build (grid-stride) ----
    for (int idx = gtid; idx < 8 * 16384; idx += NTH) {
        float x = p.wsrc[idx >> 14][idx & 16383];
        f16 h = (f16)x;
        p.wm_hi[idx] = h; p.wm_lo[idx] = (f16)(x - (float)h);
    }
    for (int idx = gtid; idx < 131072; idx += NTH) {
        int n = idx >> 8, k = idx & 255;
        float x = (k < 128) ? p.vu_wih[n * 128 + k] : p.vu_whh[n * 128 + (k - 128)];
        f16 h = (f16)x;
        p.vu_hi[idx] = h; p.vu_lo[idx] = (f16)(x - (float)h);
        float y = (k < 128) ? p.nu_wih[n * 128 + k] : p.nu_whh[n * 128 + (k - 128)];
        f16 h2 = (f16)y;
        p.nu_hi[idx] = h2; p.nu_lo[idx] = (f16)(y - (float)h2);
    }
    {
        const int total4 = NNODES * (NVARS / 4);
        const uint4* up4 = (const uint4*)p.unpack;
        for (int pidx = gtid; pidx < total4; pidx += NTH) {
            uint4 wv = up4[pidx];
            if ((wv.x | wv.y | wv.z | wv.w) == 0u) continue;
            int n  = pidx / (NVARS / 4);
            int v0 = (pidx % (NVARS / 4)) * 4;
            unsigned e[4] = { wv.x, wv.y, wv.z, wv.w };
#pragma unroll
            for (int j = 0; j < 4; ++j) {
                if (e[j]) {
                    int v = v0 + j;
                    int s1 = atomicAdd(&p.ncnt[n], 1);
                    if (s1 < CAP) p.nidx[n * CAP + s1] = v;
                    int s2 = atomicAdd(&p.vcnt[v], 1);
                    if (s2 < CAP) p.vidx[v * CAP + s2] = n;
                }
            }
        }
    }
    int ep = 1;
    gsync(p.bar, ep * NB);

    // ---- init own rows: h0 = vt ? tw+tb : fw+fb ; c0 = 0 (c in VGPRs) ----
    float cR[16];
#pragma unroll
    for (int i = 0; i < 16; ++i) cR[i] = 0.f;
#pragma unroll
    for (int i = 0; i < 12; ++i) {
        int e = threadIdx.x + i * TPB;          // 0..3071 = 24 rows x 128
        int r = e >> 7, d = e & 127;
        float hv = (p.vt[R0 + r] == 1) ? (p.true_w[d] + p.true_b[d])
                                       : (p.false_w[d] + p.false_b[d]);
        f16 hh = (f16)hv;
        hHi[r * MROW + d] = hh;
        hLo[r * MROW + d] = (f16)(hv - (float)hh);
    }
    __syncthreads();

    for (int rd = 0; rd < NROUNDS; ++rd) {
        // S1: cm MLP on own rows -> t1a (all blocks)
        layerM(hHi, hLo, p.wm_hi + 0 * 16384, p.wm_lo + 0 * 16384, p.cm_b1, true,  aHi, aLo, nullptr, 0);
        layerM(aHi, aLo, p.wm_hi + 1 * 16384, p.wm_lo + 1 * 16384, p.cm_b2, true,  bHi, bLo, nullptr, 0);
        layerM(bHi, bLo, p.wm_hi + 2 * 16384, p.wm_lo + 2 * 16384, p.cm_b3, false, nullptr, nullptr, p.t1a, R0);
        gsync(p.bar, ++ep * NB);
        // S2 (node blocks): gather children + vu LSTM + pm MLP -> t1b
        if (isNode) {
            gatherP(p.t1a, p.ncnt, p.nidx, aHi, aLo, R0);
            gatesL(aHi, aLo, hHi, hLo, cR, p.vu_hi, p.vu_lo, p.vu_bih, p.vu_bhh);
            layerM(hHi, hLo, p.wm_hi + 3 * 16384, p.wm_lo + 3 * 16384, p.pm_b1, true,  aHi, aLo, nullptr, 0);
            layerM(aHi, aLo, p.wm_hi + 4 * 16384, p.wm_lo + 4 * 16384, p.pm_b2, true,  bHi, bLo, nullptr, 0);
            layerM(bHi, bLo, p.wm_hi + 5 * 16384, p.wm_lo + 5 * 16384, p.pm_b3, false, nullptr, nullptr, p.t1b, R0);
        }
        gsync(p.bar, ++ep * NB);
        // S3 (all): gather parents + nu LSTM
        gatherP(p.t1b, p.vcnt, p.vidx, aHi, aLo, R0);
        gatesL(aHi, aLo, hHi, hLo, cR, p.nu_hi, p.nu_lo, p.nu_bih, p.nu_bhh);
    }

    // vote on leaf blocks
    if (!isNode) {
        layerM(hHi, hLo, p.wm_hi + 6 * 16384, p.wm_lo + 6 * 16384, p.vv_b1, true, aHi, aLo, nullptr, 0);
        layerM(aHi, aLo, p.wm_hi + 7 * 16384, p.wm_lo + 7 * 16384, p.vv_b2, true, bHi, bLo, nullptr, 0);
        if (threadIdx.x < 192) {
            int r = threadIdx.x >> 3, q = threadIdx.x & 7;
            float s = 0.f;
#pragma unroll
            for (int u = 0; u < 16; ++u) {
                int col = q * 16 + u;
                s += ((float)bHi[r * MROW + col] + (float)bLo[r * MROW + col]) * p.vv_w3[col];
            }
            s += __shfl_xor(s, 1);
            s += __shfl_xor(s, 2);
            s += __shfl_xor(s, 4);
            if (q == 0) p.out[R0 - NNODES + r] = s + p.vv_b3[0];
        }
    }
}

// ---------------------------------------------------------------------------
extern "C" void kernel_launch(void* const* d_in, const int* in_sizes, int n_in,
                              void* d_out, int out_size, void* d_ws, size_t ws_size,
                              hipStream_t stream) {
    Params p;
    p.vt      = (const int*)d_in[0];
    p.unpack  = (const unsigned int*)d_in[1];
    p.true_w  = (const float*)d_in[2];
    p.true_b  = (const float*)d_in[3];
    p.false_w = (const float*)d_in[4];
    p.false_b = (const float*)d_in[5];
    p.wsrc[0] = (const float*)d_in[6];  p.cm_b1 = (const float*)d_in[7];
    p.wsrc[1] = (const float*)d_in[8];  p.cm_b2 = (const float*)d_in[9];
    p.wsrc[2] = (const float*)d_in[10]; p.cm_b3 = (const float*)d_in[11];
    p.wsrc[3] = (const float*)d_in[12]; p.pm_b1 = (const float*)d_in[13];
    p.wsrc[4] = (const float*)d_in[14]; p.pm_b2 = (const float*)d_in[15];
    p.wsrc[5] = (const float*)d_in[16]; p.pm_b3 = (const float*)d_in[17];
    p.wsrc[6] = (const float*)d_in[18]; p.vv_b1 = (const float*)d_in[19];
    p.wsrc[7] = (const float*)d_in[20]; p.vv_b2 = (const float*)d_in[21];
    p.vv_w3 = (const float*)d_in[22];   p.vv_b3 = (const float*)d_in[23];
    p.vu_wih = (const float*)d_in[24];  p.vu_whh = (const float*)d_in[25];
    p.vu_bih = (const float*)d_in[26];  p.vu_bhh = (const float*)d_in[27];
    p.nu_wih = (const float*)d_in[28];  p.nu_whh = (const float*)d_in[29];
    p.nu_bih = (const float*)d_in[30];  p.nu_bhh = (const float*)d_in[31];

    // workspace layout
    float* t1a = (float*)d_ws;                   // [12000][128]
    float* t1b = t1a + (size_t)NVARS * 128;
    int* ncnt = (int*)(t1b + (size_t)NVARS * 128);
    int* nidx = ncnt + NNODES;                   // [NNODES][CAP]
    int* vcnt = nidx + NNODES * CAP;
    int* vidx = vcnt + NVARS;                    // [NVARS][CAP]
    int* bar  = vidx + NVARS * CAP;
    uintptr_t wb = (uintptr_t)(bar + 16);
    wb = (wb + 15) & ~(uintptr_t)15;
    f16* wm_hi = (f16*)wb;            // 8*16384
    f16* wm_lo = wm_hi + 131072;
    f16* vu_hi = wm_lo + 131072;      // 512*256
    f16* vu_lo = vu_hi + 131072;
    f16* nu_hi = vu_lo + 131072;
    f16* nu_lo = nu_hi + 131072;

    p.t1a = t1a; p.t1b = t1b; p.bar = bar;
    p.ncnt = ncnt; p.nidx = nidx; p.vcnt = vcnt; p.vidx = vidx;
    p.wm_hi = wm_hi; p.wm_lo = wm_lo;
    p.vu_hi = vu_hi; p.vu_lo = vu_lo; p.nu_hi = nu_hi; p.nu_lo = nu_lo;
    p.out = (float*)d_out;

    (void)hipMemsetAsync(ncnt, 0, NNODES * sizeof(int), stream);
    (void)hipMemsetAsync(vcnt, 0, NVARS * sizeof(int), stream);
    (void)hipMemsetAsync(bar, 0, 16 * sizeof(int), stream);
    mega<<<NB, TPB, 0, stream>>>(p);
}

// Round 11
// 3671.633 us; speedup vs baseline: 2.9152x; 2.9152x over previous
//
#include <hip/hip_runtime.h>

#define NVARS    12000
#define NNODES   8400
#define NLEAF    3600
#define NROUNDS  12
#define RPB      48              // rows per block
#define NB       250             // 250*48 = 12000; node boundary = 175*48 = 8400
#define NODE_BLKS 175
#define CAP      64
#define TPB      256             // 4 waves/block, 1 block/CU
#define NTH      (NB * TPB)

typedef _Float16 f16;
typedef _Float16 half8 __attribute__((ext_vector_type(8)));
typedef _Float16 half4v __attribute__((ext_vector_type(4)));
typedef float f32x4 __attribute__((ext_vector_type(4)));

#define MROW 136                 // LDS plane row stride (halves); 272 B
#define PLANE (RPB * MROW)       // 6528 halves

struct Params {
    float *t1a, *t1b;
    int *bar;
    const int *vt;
    int *ncnt, *nidx, *vcnt, *vidx;
    const unsigned int *unpack;
    const float *true_w, *true_b, *false_w, *false_b;
    const float *wsrc[8];
    const float *vu_wih, *vu_whh, *nu_wih, *nu_whh;
    f16 *wm_hi, *wm_lo;                // 8 * 16384, [n][k]
    f16 *vu_hi, *vu_lo, *nu_hi, *nu_lo;// [512][256]
    const float *cm_b1, *cm_b2, *cm_b3, *pm_b1, *pm_b2, *pm_b3;
    const float *vv_b1, *vv_b2, *vv_w3, *vv_b3;
    const float *vu_bih, *vu_bhh, *nu_bih, *nu_bhh;
    float *out;
};

__device__ __forceinline__ float sigm(float x) { return 1.f / (1.f + expf(-x)); }

// agent-coherent scalar access (sc1): bypasses non-coherent XCD L2s -> no fence needed
__device__ __forceinline__ float ldA(const float* p) {
    return __hip_atomic_load(p, __ATOMIC_RELAXED, __HIP_MEMORY_SCOPE_AGENT);
}
__device__ __forceinline__ void stA(float* p, float v) {
    __hip_atomic_store(p, v, __ATOMIC_RELAXED, __HIP_MEMORY_SCOPE_AGENT);
}

// ---- light grid barrier: NO agent fence (no L2 flush). Cross-block data goes sc1.
__device__ __forceinline__ void gsync(int* bar, int target) {
    __syncthreads();
    __builtin_amdgcn_fence(__ATOMIC_RELEASE, "workgroup");   // waitcnt drain, no wbl2
    if (threadIdx.x == 0) {
        __hip_atomic_fetch_add(bar, 1, __ATOMIC_RELAXED, __HIP_MEMORY_SCOPE_AGENT);
        while (__hip_atomic_load(bar, __ATOMIC_RELAXED, __HIP_MEMORY_SCOPE_AGENT) < target)
            __builtin_amdgcn_s_sleep(16);
    }
    __builtin_amdgcn_fence(__ATOMIC_ACQUIRE, "workgroup");
    __syncthreads();
}

// ---- full barrier (prologue only): normal-store data handoff needs the L2 flush
__device__ __forceinline__ void gsyncFull(int* bar, int target) {
    __syncthreads();
    __threadfence();
    if (threadIdx.x == 0) {
        atomicAdd(bar, 1);
        while (__hip_atomic_load(bar, __ATOMIC_RELAXED, __HIP_MEMORY_SCOPE_AGENT) < target)
            __builtin_amdgcn_s_sleep(16);
    }
    __syncthreads();
    __threadfence();
}

// near-fp32 split product: (Ah+Al)*(Bh+Bl) minus negligible Al*Bl
__device__ __forceinline__ f32x4 mfma3(half8 ah, half8 al, half8 bh, half8 bl, f32x4 acc) {
    acc = __builtin_amdgcn_mfma_f32_16x16x32_f16(ah, bh, acc, 0, 0, 0);
    acc = __builtin_amdgcn_mfma_f32_16x16x32_f16(al, bh, acc, 0, 0, 0);
    acc = __builtin_amdgcn_mfma_f32_16x16x32_f16(ah, bl, acc, 0, 0, 0);
    return acc;
}

// ---- one 128->128 MLP layer over the block's 48 rows; wave w owns cols [32w,32w+32)
__device__ void layerM(const f16* inHi, const f16* inLo,
                       const f16* Wh, const f16* Wl, const float* bias, bool relu,
                       f16* outHi, f16* outLo, float* gdst, int grow0) {
    const int lane = threadIdx.x & 63, l15 = lane & 15, quad = lane >> 4;
    const int w = threadIdx.x >> 6;
    half8 Bh[2][4], Bl[2][4];
#pragma unroll
    for (int ct = 0; ct < 2; ++ct)
#pragma unroll
        for (int s = 0; s < 4; ++s) {
            size_t off = (size_t)(w * 32 + ct * 16 + l15) * 128 + s * 32 + quad * 8;
            Bh[ct][s] = *(const half8*)(Wh + off);
            Bl[ct][s] = *(const half8*)(Wl + off);
        }
    float b0 = bias[w * 32 + l15], b1 = bias[w * 32 + 16 + l15];
#pragma unroll
    for (int mt = 0; mt < 3; ++mt) {
        half8 Ah[4], Al[4];
#pragma unroll
        for (int s = 0; s < 4; ++s) {
            int off = (mt * 16 + l15) * MROW + s * 32 + quad * 8;
            Ah[s] = *(const half8*)(inHi + off);
            Al[s] = *(const half8*)(inLo + off);
        }
        f32x4 acc0 = {0.f, 0.f, 0.f, 0.f}, acc1 = {0.f, 0.f, 0.f, 0.f};
#pragma unroll
        for (int s = 0; s < 4; ++s) {
            acc0 = mfma3(Ah[s], Al[s], Bh[0][s], Bl[0][s], acc0);
            acc1 = mfma3(Ah[s], Al[s], Bh[1][s], Bl[1][s], acc1);
        }
#pragma unroll
        for (int ct = 0; ct < 2; ++ct) {
            f32x4 a = ct ? acc1 : acc0;
            float bb = ct ? b1 : b0;
            int col = w * 32 + ct * 16 + l15;
#pragma unroll
            for (int reg = 0; reg < 4; ++reg) {
                int row = mt * 16 + quad * 4 + reg;
                float v = a[reg] + bb;
                if (relu) v = fmaxf(v, 0.f);
                if (gdst) {
                    stA(&gdst[(size_t)(grow0 + row) * 128 + col], v);   // sc1 write-through
                } else {
                    f16 hh = (f16)v;
                    outHi[row * MROW + col] = hh;
                    outLo[row * MROW + col] = (f16)(v - (float)hh);
                }
            }
        }
    }
    __syncthreads();
}

// ---- LSTM over the block's 48 rows: A=[msg;h] K=256, 512 gate cols; c in VGPRs.
__device__ void gatesL(const f16* msgHi, const f16* msgLo, f16* hHi, f16* hLo, float* cR,
                       const f16* Wh, const f16* Wl, const float* bih, const float* bhh) {
    const int lane = threadIdx.x & 63, l15 = lane & 15, quad = lane >> 4;
    const int w = threadIdx.x >> 6;
    float gb[4][2];
#pragma unroll
    for (int g = 0; g < 4; ++g)
#pragma unroll
        for (int c2 = 0; c2 < 2; ++c2) {
            int col = g * 128 + w * 32 + c2 * 16 + l15;
            gb[g][c2] = bih[col] + bhh[col];
        }
    f32x4 acc[3][4][2];
#pragma unroll
    for (int mt = 0; mt < 3; ++mt)
#pragma unroll
        for (int g = 0; g < 4; ++g)
#pragma unroll
            for (int c2 = 0; c2 < 2; ++c2)
                acc[mt][g][c2] = (f32x4){0.f, 0.f, 0.f, 0.f};

    for (int g = 0; g < 4; ++g) {
        half8 Bh[2][8], Bl[2][8];       // resident per gate (r7-proven)
#pragma unroll
        for (int c2 = 0; c2 < 2; ++c2)
#pragma unroll
            for (int s = 0; s < 8; ++s) {
                size_t off = (size_t)(g * 128 + w * 32 + c2 * 16 + l15) * 256 + s * 32 + quad * 8;
                Bh[c2][s] = *(const half8*)(Wh + off);
                Bl[c2][s] = *(const half8*)(Wl + off);
            }
#pragma unroll
        for (int mt = 0; mt < 3; ++mt) {
            half8 Ah[8], Al[8];
#pragma unroll
            for (int s = 0; s < 4; ++s) {
                int off = (mt * 16 + l15) * MROW + s * 32 + quad * 8;
                Ah[s]     = *(const half8*)(msgHi + off);
                Al[s]     = *(const half8*)(msgLo + off);
                Ah[s + 4] = *(const half8*)(hHi + off);
                Al[s + 4] = *(const half8*)(hLo + off);
            }
#pragma unroll
            for (int c2 = 0; c2 < 2; ++c2)
#pragma unroll
                for (int s = 0; s < 8; ++s)
                    acc[mt][g][c2] = mfma3(Ah[s], Al[s], Bh[c2][s], Bl[c2][s], acc[mt][g][c2]);
        }
    }
    __syncthreads();
#pragma unroll
    for (int mt = 0; mt < 3; ++mt)
#pragma unroll
        for (int c2 = 0; c2 < 2; ++c2) {
            int col = w * 32 + c2 * 16 + l15;
#pragma unroll
            for (int reg = 0; reg < 4; ++reg) {
                int row = mt * 16 + quad * 4 + reg;
                float gi = acc[mt][0][c2][reg] + gb[0][c2];
                float gf = acc[mt][1][c2][reg] + gb[1][c2];
                float gg = acc[mt][2][c2][reg] + gb[2][c2];
                float go = acc[mt][3][c2][reg] + gb[3][c2];
                float cv = cR[(mt * 2 + c2) * 4 + reg];
                float cn = sigm(gf) * cv + sigm(gi) * tanhf(gg);
                float hn = sigm(go) * tanhf(cn);
                cR[(mt * 2 + c2) * 4 + reg] = cn;
                f16 hh = (f16)hn;
                hHi[row * MROW + col] = hh;
                hLo[row * MROW + col] = (f16)(hn - (float)hh);
            }
        }
    __syncthreads();
}

// ---- gather own 48 rows from t1 (sc1 loads, hand-pipelined over edges)
__device__ void gatherP(const float* t1g, const int* cnt, const int* idxm,
                        f16* msgHi, f16* msgLo, int R0) {
    if (threadIdx.x < 192) {
        int r = threadIdx.x >> 2, q = threadIdx.x & 3;   // 48 rows x 4 col-segments (32 each)
        int row = R0 + r;
        int n = cnt[row]; if (n > CAP) n = CAP;
        const int* ir = idxm + (size_t)row * CAP;
        float a[32];
#pragma unroll
        for (int u = 0; u < 32; ++u) a[u] = 0.f;
        if (n > 0) {
            float cur[32];
            const float* src = t1g + (size_t)ir[0] * 128 + q * 32;
#pragma unroll
            for (int u = 0; u < 32; ++u) cur[u] = ldA(src + u);
            for (int j = 1; j < n; ++j) {
                float nxt[32];
                const float* s2 = t1g + (size_t)ir[j] * 128 + q * 32;
#pragma unroll
                for (int u = 0; u < 32; ++u) nxt[u] = ldA(s2 + u);
#pragma unroll
                for (int u = 0; u < 32; ++u) { a[u] += cur[u]; cur[u] = nxt[u]; }
            }
#pragma unroll
            for (int u = 0; u < 32; ++u) a[u] += cur[u];
        }
#pragma unroll
        for (int u4 = 0; u4 < 8; ++u4) {
            half4v hh, ll;
#pragma unroll
            for (int k = 0; k < 4; ++k) {
                float x = a[u4 * 4 + k];
                f16 h = (f16)x;
                hh[k] = h; ll[k] = (f16)(x - (float)h);
            }
            int off = r * MROW + q * 32 + u4 * 4;
            *(half4v*)(msgHi + off) = hh;
            *(half4v*)(msgLo + off) = ll;
        }
    }
    __syncthreads();
}

// ---------------------------------------------------------------------------
__global__ void __launch_bounds__(TPB, 1) mega(Params p) {
    __shared__ __align__(16) f16 smh[6 * PLANE];   // 78.3 KB
    f16 *hHi = smh,             *hLo = smh + PLANE;
    f16 *aHi = smh + 2 * PLANE, *aLo = smh + 3 * PLANE;
    f16 *bHi = smh + 4 * PLANE, *bLo = smh + 5 * PLANE;

    const int R0 = blockIdx.x * RPB;
    const bool isNode = blockIdx.x < NODE_BLKS;
    const int gtid = blockIdx.x * TPB + threadIdx.x;

    // ---- prologue (grid-stride): weight split + CSR build, one FULL fence after ----
    for (int idx = gtid; idx < 8 * 16384; idx += NTH) {
        float x = p.wsrc[idx >> 14][idx & 16383];
        f16 h = (f16)x;
        p.wm_hi[idx] = h; p.wm_lo[idx] = (f16)(x - (float)h);
    }
    for (int idx = gtid; idx < 131072; idx += NTH) {
        int n = idx >> 8, k = idx & 255;
        float x = (k < 128) ? p.vu_wih[n * 128 + k] : p.vu_whh[n * 128 + (k - 128)];
        f16 h = (f16)x;
        p.vu_hi[idx] = h; p.vu_lo[idx] = (f16)(x - (float)h);
        float y = (k < 128) ? p.nu_wih[n * 128 + k] : p.nu_whh[n * 128 + (k - 128)];
        f16 h2 = (f16)y;
        p.nu_hi[idx] = h2; p.nu_lo[idx] = (f16)(y - (float)h2);
    }
    {
        const int total4 = NNODES * (NVARS / 4);
        const uint4* up4 = (const uint4*)p.unpack;
        for (int pidx = gtid; pidx < total4; pidx += NTH) {
            uint4 wv = up4[pidx];
            if ((wv.x | wv.y | wv.z | wv.w) == 0u) continue;
            int n  = pidx / (NVARS / 4);
            int v0 = (pidx % (NVARS / 4)) * 4;
            unsigned e[4] = { wv.x, wv.y, wv.z, wv.w };
#pragma unroll
            for (int j = 0; j < 4; ++j) {
                if (e[j]) {
                    int v = v0 + j;
                    int s1 = atomicAdd(&p.ncnt[n], 1);
                    if (s1 < CAP) p.nidx[n * CAP + s1] = v;
                    int s2 = atomicAdd(&p.vcnt[v], 1);
                    if (s2 < CAP) p.vidx[v * CAP + s2] = n;
                }
            }
        }
    }
    int ep = 1;
    gsyncFull(p.bar, ep * NB);    // one-time L2 flush; weights stay L2-hot afterwards

    // ---- init own rows: h0; c0 = 0 in VGPRs ----
    float cR[24];
#pragma unroll
    for (int i = 0; i < 24; ++i) cR[i] = 0.f;
#pragma unroll
    for (int i = 0; i < 24; ++i) {
        int e = threadIdx.x + i * TPB;          // 0..6143 = 48 rows x 128
        int r = e >> 7, d = e & 127;
        float hv = (p.vt[R0 + r] == 1) ? (p.true_w[d] + p.true_b[d])
                                       : (p.false_w[d] + p.false_b[d]);
        f16 hh = (f16)hv;
        hHi[r * MROW + d] = hh;
        hLo[r * MROW + d] = (f16)(hv - (float)hh);
    }
    __syncthreads();

    for (int rd = 0; rd < NROUNDS; ++rd) {
        // S1: cm MLP on own rows -> t1a (sc1)
        layerM(hHi, hLo, p.wm_hi + 0 * 16384, p.wm_lo + 0 * 16384, p.cm_b1, true,  aHi, aLo, nullptr, 0);
        layerM(aHi, aLo, p.wm_hi + 1 * 16384, p.wm_lo + 1 * 16384, p.cm_b2, true,  bHi, bLo, nullptr, 0);
        layerM(bHi, bLo, p.wm_hi + 2 * 16384, p.wm_lo + 2 * 16384, p.cm_b3, false, nullptr, nullptr, p.t1a, R0);
        gsync(p.bar, ++ep * NB);
        // S2 (node blocks): gather children + vu LSTM + pm MLP -> t1b (sc1)
        if (isNode) {
            gatherP(p.t1a, p.ncnt, p.nidx, aHi, aLo, R0);
            gatesL(aHi, aLo, hHi, hLo, cR, p.vu_hi, p.vu_lo, p.vu_bih, p.vu_bhh);
            layerM(hHi, hLo, p.wm_hi + 3 * 16384, p.wm_lo + 3 * 16384, p.pm_b1, true,  aHi, aLo, nullptr, 0);
            layerM(aHi, aLo, p.wm_hi + 4 * 16384, p.wm_lo + 4 * 16384, p.pm_b2, true,  bHi, bLo, nullptr, 0);
            layerM(bHi, bLo, p.wm_hi + 5 * 16384, p.wm_lo + 5 * 16384, p.pm_b3, false, nullptr, nullptr, p.t1b, R0);
        }
        gsync(p.bar, ++ep * NB);
        // S3 (all): gather parents + nu LSTM
        gatherP(p.t1b, p.vcnt, p.vidx, aHi, aLo, R0);
        gatesL(aHi, aLo, hHi, hLo, cR, p.nu_hi, p.nu_lo, p.nu_bih, p.nu_bhh);
    }

    // vote on leaf blocks
    if (!isNode) {
        layerM(hHi, hLo, p.wm_hi + 6 * 16384, p.wm_lo + 6 * 16384, p.vv_b1, true, aHi, aLo, nullptr, 0);
        layerM(aHi, aLo, p.wm_hi + 7 * 16384, p.wm_lo + 7 * 16384, p.vv_b2, true, bHi, bLo, nullptr, 0);
        if (threadIdx.x < 192) {
            int r = threadIdx.x >> 2, q = threadIdx.x & 3;
            float s = 0.f;
#pragma unroll
            for (int u = 0; u < 32; ++u) {
                int col = q * 32 + u;
                s += ((float)bHi[r * MROW + col] + (float)bLo[r * MROW + col]) * p.vv_w3[col];
            }
            s += __shfl_xor(s, 1);
            s += __shfl_xor(s, 2);
            if (q == 0) p.out[R0 - NNODES + r] = s + p.vv_b3[0];
        }
    }
}

// ---------------------------------------------------------------------------
extern "C" void kernel_launch(void* const* d_in, const int* in_sizes, int n_in,
                              void* d_out, int out_size, void* d_ws, size_t ws_size,
                              hipStream_t stream) {
    Params p;
    p.vt      = (const int*)d_in[0];
    p.unpack  = (const unsigned int*)d_in[1];
    p.true_w  = (const float*)d_in[2];
    p.true_b  = (const float*)d_in[3];
    p.false_w = (const float*)d_in[4];
    p.false_b = (const float*)d_in[5];
    p.wsrc[0] = (const float*)d_in[6];  p.cm_b1 = (const float*)d_in[7];
    p.wsrc[1] = (const float*)d_in[8];  p.cm_b2 = (const float*)d_in[9];
    p.wsrc[2] = (const float*)d_in[10]; p.cm_b3 = (const float*)d_in[11];
    p.wsrc[3] = (const float*)d_in[12]; p.pm_b1 = (const float*)d_in[13];
    p.wsrc[4] = (const float*)d_in[14]; p.pm_b2 = (const float*)d_in[15];
    p.wsrc[5] = (const float*)d_in[16]; p.pm_b3 = (const float*)d_in[17];
    p.wsrc[6] = (const float*)d_in[18]; p.vv_b1 = (const float*)d_in[19];
    p.wsrc[7] = (const float*)d_in[20]; p.vv_b2 = (const float*)d_in[21];
    p.vv_w3 = (const float*)d_in[22];   p.vv_b3 = (const float*)d_in[23];
    p.vu_wih = (const float*)d_in[24];  p.vu_whh = (const float*)d_in[25];
    p.vu_bih = (const float*)d_in[26];  p.vu_bhh = (const float*)d_in[27];
    p.nu_wih = (const float*)d_in[28];  p.nu_whh = (const float*)d_in[29];
    p.nu_bih = (const float*)d_in[30];  p.nu_bhh = (const float*)d_in[31];

    float* t1a = (float*)d_ws;                   // [12000][128]
    float* t1b = t1a + (size_t)NVARS * 128;
    int* ncnt = (int*)(t1b + (size_t)NVARS * 128);
    int* nidx = ncnt + NNODES;                   // [NNODES][CAP]
    int* vcnt = nidx + NNODES * CAP;
    int* vidx = vcnt + NVARS;                    // [NVARS][CAP]
    int* bar  = vidx + NVARS * CAP;
    uintptr_t wb = (uintptr_t)(bar + 16);
    wb = (wb + 15) & ~(uintptr_t)15;
    f16* wm_hi = (f16*)wb;            // 8*16384
    f16* wm_lo = wm_hi + 131072;
    f16* vu_hi = wm_lo + 131072;      // 512*256
    f16* vu_lo = vu_hi + 131072;
    f16* nu_hi = vu_lo + 131072;
    f16* nu_lo = nu_hi + 131072;

    p.t1a = t1a; p.t1b = t1b; p.bar = bar;
    p.ncnt = ncnt; p.nidx = nidx; p.vcnt = vcnt; p.vidx = vidx;
    p.wm_hi = wm_hi; p.wm_lo = wm_lo;
    p.vu_hi = vu_hi; p.vu_lo = vu_lo; p.nu_hi = nu_hi; p.nu_lo = nu_lo;
    p.out = (float*)d_out;

    (void)hipMemsetAsync(ncnt, 0, NNODES * sizeof(int), stream);
    (void)hipMemsetAsync(vcnt, 0, NVARS * sizeof(int), stream);
    (void)hipMemsetAsync(bar, 0, 16 * sizeof(int), stream);
    mega<<<NB, TPB, 0, stream>>>(p);
}

// Round 12
// 3602.120 us; speedup vs baseline: 2.9714x; 1.0193x over previous
//
#include <hip/hip_runtime.h>

#define NVARS    12000
#define NNODES   8400
#define NLEAF    3600
#define NROUNDS  12
#define RPB      48              // rows per block
#define NB       250             // 250*48 = 12000; node boundary = 175*48 = 8400
#define NODE_BLKS 175
#define CAP      64
#define TPB      256             // 4 waves/block, 1 block/CU
#define NTH      (NB * TPB)
#define BSLOT    32              // ints between arrival slots (128 B)

typedef _Float16 f16;
typedef _Float16 half8 __attribute__((ext_vector_type(8)));
typedef _Float16 half4v __attribute__((ext_vector_type(4)));
typedef float f32x4 __attribute__((ext_vector_type(4)));

#define MROW 136                 // LDS plane row stride (halves); 272 B
#define PLANE (RPB * MROW)       // 6528 halves

struct Params {
    float *t1a, *t1b;
    int *bar;                    // 8 slots x BSLOT ints
    const int *vt;
    int *ncnt, *nidx, *vcnt, *vidx;
    const unsigned int *unpack;
    const float *true_w, *true_b, *false_w, *false_b;
    const float *wsrc[8];
    const float *vu_wih, *vu_whh, *nu_wih, *nu_whh;
    f16 *wm_hi, *wm_lo;                // 8 * 16384, [n][k]
    f16 *vu_hi, *vu_lo, *nu_hi, *nu_lo;// [512][256]
    const float *cm_b1, *cm_b2, *cm_b3, *pm_b1, *pm_b2, *pm_b3;
    const float *vv_b1, *vv_b2, *vv_w3, *vv_b3;
    const float *vu_bih, *vu_bhh, *nu_bih, *nu_bhh;
    float *out;
};

__device__ __forceinline__ float sigm(float x) { return 1.f / (1.f + expf(-x)); }

// ---- grid barrier: threadfence for data visibility (r7-proven), but arrivals
// spread over 8 cachelines and pollers use plain relaxed LOADS (no RMW storm).
__device__ __forceinline__ void gsync(int* bar, int target) {
    __syncthreads();
    __threadfence();
    if (threadIdx.x == 0) {
        __hip_atomic_fetch_add(&bar[(blockIdx.x & 7) * BSLOT], 1,
                               __ATOMIC_RELAXED, __HIP_MEMORY_SCOPE_AGENT);
        for (;;) {
            int sum = 0;
#pragma unroll
            for (int k = 0; k < 8; ++k)
                sum += __hip_atomic_load(&bar[k * BSLOT], __ATOMIC_RELAXED,
                                         __HIP_MEMORY_SCOPE_AGENT);
            if (sum >= target) break;
            __builtin_amdgcn_s_sleep(32);
        }
    }
    __syncthreads();
    __threadfence();
}

// near-fp32 split product: (Ah+Al)*(Bh+Bl) minus negligible Al*Bl
__device__ __forceinline__ f32x4 mfma3(half8 ah, half8 al, half8 bh, half8 bl, f32x4 acc) {
    acc = __builtin_amdgcn_mfma_f32_16x16x32_f16(ah, bh, acc, 0, 0, 0);
    acc = __builtin_amdgcn_mfma_f32_16x16x32_f16(al, bh, acc, 0, 0, 0);
    acc = __builtin_amdgcn_mfma_f32_16x16x32_f16(ah, bl, acc, 0, 0, 0);
    return acc;
}

// ---- one 128->128 MLP layer over the block's 48 rows; wave w owns cols [32w,32w+32)
__device__ void layerM(const f16* inHi, const f16* inLo,
                       const f16* Wh, const f16* Wl, const float* bias, bool relu,
                       f16* outHi, f16* outLo, float* gdst, int grow0) {
    const int lane = threadIdx.x & 63, l15 = lane & 15, quad = lane >> 4;
    const int w = threadIdx.x >> 6;
    half8 Bh[2][4], Bl[2][4];
#pragma unroll
    for (int ct = 0; ct < 2; ++ct)
#pragma unroll
        for (int s = 0; s < 4; ++s) {
            size_t off = (size_t)(w * 32 + ct * 16 + l15) * 128 + s * 32 + quad * 8;
            Bh[ct][s] = *(const half8*)(Wh + off);
            Bl[ct][s] = *(const half8*)(Wl + off);
        }
    float b0 = bias[w * 32 + l15], b1 = bias[w * 32 + 16 + l15];
#pragma unroll
    for (int mt = 0; mt < 3; ++mt) {
        half8 Ah[4], Al[4];
#pragma unroll
        for (int s = 0; s < 4; ++s) {
            int off = (mt * 16 + l15) * MROW + s * 32 + quad * 8;
            Ah[s] = *(const half8*)(inHi + off);
            Al[s] = *(const half8*)(inLo + off);
        }
        f32x4 acc0 = {0.f, 0.f, 0.f, 0.f}, acc1 = {0.f, 0.f, 0.f, 0.f};
#pragma unroll
        for (int s = 0; s < 4; ++s) {
            acc0 = mfma3(Ah[s], Al[s], Bh[0][s], Bl[0][s], acc0);
            acc1 = mfma3(Ah[s], Al[s], Bh[1][s], Bl[1][s], acc1);
        }
#pragma unroll
        for (int ct = 0; ct < 2; ++ct) {
            f32x4 a = ct ? acc1 : acc0;
            float bb = ct ? b1 : b0;
            int col = w * 32 + ct * 16 + l15;
#pragma unroll
            for (int reg = 0; reg < 4; ++reg) {
                int row = mt * 16 + quad * 4 + reg;
                float v = a[reg] + bb;
                if (relu) v = fmaxf(v, 0.f);
                if (gdst) {
                    gdst[(size_t)(grow0 + row) * 128 + col] = v;   // plain store
                } else {
                    f16 hh = (f16)v;
                    outHi[row * MROW + col] = hh;
                    outLo[row * MROW + col] = (f16)(v - (float)hh);
                }
            }
        }
    }
    __syncthreads();
}

// ---- LSTM over the block's 48 rows: A=[msg;h] K=256, 512 gate cols; c in VGPRs.
__device__ void gatesL(const f16* msgHi, const f16* msgLo, f16* hHi, f16* hLo, float* cR,
                       const f16* Wh, const f16* Wl, const float* bih, const float* bhh) {
    const int lane = threadIdx.x & 63, l15 = lane & 15, quad = lane >> 4;
    const int w = threadIdx.x >> 6;
    float gb[4][2];
#pragma unroll
    for (int g = 0; g < 4; ++g)
#pragma unroll
        for (int c2 = 0; c2 < 2; ++c2) {
            int col = g * 128 + w * 32 + c2 * 16 + l15;
            gb[g][c2] = bih[col] + bhh[col];
        }
    f32x4 acc[3][4][2];
#pragma unroll
    for (int mt = 0; mt < 3; ++mt)
#pragma unroll
        for (int g = 0; g < 4; ++g)
#pragma unroll
            for (int c2 = 0; c2 < 2; ++c2)
                acc[mt][g][c2] = (f32x4){0.f, 0.f, 0.f, 0.f};

    for (int g = 0; g < 4; ++g) {
        half8 Bh[2][8], Bl[2][8];       // resident per gate (r7-proven)
#pragma unroll
        for (int c2 = 0; c2 < 2; ++c2)
#pragma unroll
            for (int s = 0; s < 8; ++s) {
                size_t off = (size_t)(g * 128 + w * 32 + c2 * 16 + l15) * 256 + s * 32 + quad * 8;
                Bh[c2][s] = *(const half8*)(Wh + off);
                Bl[c2][s] = *(const half8*)(Wl + off);
            }
#pragma unroll
        for (int mt = 0; mt < 3; ++mt) {
            half8 Ah[8], Al[8];
#pragma unroll
            for (int s = 0; s < 4; ++s) {
                int off = (mt * 16 + l15) * MROW + s * 32 + quad * 8;
                Ah[s]     = *(const half8*)(msgHi + off);
                Al[s]     = *(const half8*)(msgLo + off);
                Ah[s + 4] = *(const half8*)(hHi + off);
                Al[s + 4] = *(const half8*)(hLo + off);
            }
#pragma unroll
            for (int c2 = 0; c2 < 2; ++c2)
#pragma unroll
                for (int s = 0; s < 8; ++s)
                    acc[mt][g][c2] = mfma3(Ah[s], Al[s], Bh[c2][s], Bl[c2][s], acc[mt][g][c2]);
        }
    }
    __syncthreads();
#pragma unroll
    for (int mt = 0; mt < 3; ++mt)
#pragma unroll
        for (int c2 = 0; c2 < 2; ++c2) {
            int col = w * 32 + c2 * 16 + l15;
#pragma unroll
            for (int reg = 0; reg < 4; ++reg) {
                int row = mt * 16 + quad * 4 + reg;
                float gi = acc[mt][0][c2][reg] + gb[0][c2];
                float gf = acc[mt][1][c2][reg] + gb[1][c2];
                float gg = acc[mt][2][c2][reg] + gb[2][c2];
                float go = acc[mt][3][c2][reg] + gb[3][c2];
                float cv = cR[(mt * 2 + c2) * 4 + reg];
                float cn = sigm(gf) * cv + sigm(gi) * tanhf(gg);
                float hn = sigm(go) * tanhf(cn);
                cR[(mt * 2 + c2) * 4 + reg] = cn;
                f16 hh = (f16)hn;
                hHi[row * MROW + col] = hh;
                hLo[row * MROW + col] = (f16)(hn - (float)hh);
            }
        }
    __syncthreads();
}

// ---- gather own 48 rows from t1 (plain float4 loads, 2-deep edge pipeline)
__device__ void gatherP(const float* t1g, const int* cnt, const int* idxm,
                        f16* msgHi, f16* msgLo, int R0) {
    if (threadIdx.x < 192) {
        int r = threadIdx.x >> 2, q = threadIdx.x & 3;   // 48 rows x 4 segs (32 floats)
        int row = R0 + r;
        int n = cnt[row]; if (n > CAP) n = CAP;
        const int* ir = idxm + (size_t)row * CAP;
        float a[32];
#pragma unroll
        for (int u = 0; u < 32; ++u) a[u] = 0.f;
        if (n > 0) {
            float4 cur[8];
            const float4* s4 = (const float4*)(t1g + (size_t)ir[0] * 128) + q * 8;
#pragma unroll
            for (int u = 0; u < 8; ++u) cur[u] = s4[u];
            for (int j = 1; j < n; ++j) {
                float4 nxt[8];
                const float4* s2 = (const float4*)(t1g + (size_t)ir[j] * 128) + q * 8;
#pragma unroll
                for (int u = 0; u < 8; ++u) nxt[u] = s2[u];
#pragma unroll
                for (int u = 0; u < 8; ++u) {
                    a[u * 4 + 0] += cur[u].x; a[u * 4 + 1] += cur[u].y;
                    a[u * 4 + 2] += cur[u].z; a[u * 4 + 3] += cur[u].w;
                    cur[u] = nxt[u];
                }
            }
#pragma unroll
            for (int u = 0; u < 8; ++u) {
                a[u * 4 + 0] += cur[u].x; a[u * 4 + 1] += cur[u].y;
                a[u * 4 + 2] += cur[u].z; a[u * 4 + 3] += cur[u].w;
            }
        }
#pragma unroll
        for (int u4 = 0; u4 < 8; ++u4) {
            half4v hh, ll;
#pragma unroll
            for (int k = 0; k < 4; ++k) {
                float x = a[u4 * 4 + k];
                f16 h = (f16)x;
                hh[k] = h; ll[k] = (f16)(x - (float)h);
            }
            int off = r * MROW + q * 32 + u4 * 4;
            *(half4v*)(msgHi + off) = hh;
            *(half4v*)(msgLo + off) = ll;
        }
    }
    __syncthreads();
}

// ---------------------------------------------------------------------------
__global__ void __launch_bounds__(TPB, 1) mega(Params p) {
    __shared__ __align__(16) f16 smh[6 * PLANE];   // 78.3 KB
    f16 *hHi = smh,             *hLo = smh + PLANE;
    f16 *aHi = smh + 2 * PLANE, *aLo = smh + 3 * PLANE;
    f16 *bHi = smh + 4 * PLANE, *bLo = smh + 5 * PLANE;

    const int R0 = blockIdx.x * RPB;
    const bool isNode = blockIdx.x < NODE_BLKS;
    const int gtid = blockIdx.x * TPB + threadIdx.x;

    // ---- prologue (grid-stride): weight split + CSR build ----
    for (int idx = gtid; idx < 8 * 16384; idx += NTH) {
        float x = p.wsrc[idx >> 14][idx & 16383];
        f16 h = (f16)x;
        p.wm_hi[idx] = h; p.wm_lo[idx] = (f16)(x - (float)h);
    }
    for (int idx = gtid; idx < 131072; idx += NTH) {
        int n = idx >> 8, k = idx & 255;
        float x = (k < 128) ? p.vu_wih[n * 128 + k] : p.vu_whh[n * 128 + (k - 128)];
        f16 h = (f16)x;
        p.vu_hi[idx] = h; p.vu_lo[idx] = (f16)(x - (float)h);
        float y = (k < 128) ? p.nu_wih[n * 128 + k] : p.nu_whh[n * 128 + (k - 128)];
        f16 h2 = (f16)y;
        p.nu_hi[idx] = h2; p.nu_lo[idx] = (f16)(y - (float)h2);
    }
    {
        const int total4 = NNODES * (NVARS / 4);
        const uint4* up4 = (const uint4*)p.unpack;
        for (int pidx = gtid; pidx < total4; pidx += NTH) {
            uint4 wv = up4[pidx];
            if ((wv.x | wv.y | wv.z | wv.w) == 0u) continue;
            int n  = pidx / (NVARS / 4);
            int v0 = (pidx % (NVARS / 4)) * 4;
            unsigned e[4] = { wv.x, wv.y, wv.z, wv.w };
#pragma unroll
            for (int j = 0; j < 4; ++j) {
                if (e[j]) {
                    int v = v0 + j;
                    int s1 = atomicAdd(&p.ncnt[n], 1);
                    if (s1 < CAP) p.nidx[n * CAP + s1] = v;
                    int s2 = atomicAdd(&p.vcnt[v], 1);
                    if (s2 < CAP) p.vidx[v * CAP + s2] = n;
                }
            }
        }
    }
    int ep = 1;
    gsync(p.bar, ep * NB);

    // ---- init own rows: h0; c0 = 0 in VGPRs ----
    float cR[24];
#pragma unroll
    for (int i = 0; i < 24; ++i) cR[i] = 0.f;
#pragma unroll
    for (int i = 0; i < 24; ++i) {
        int e = threadIdx.x + i * TPB;          // 0..6143 = 48 rows x 128
        int r = e >> 7, d = e & 127;
        float hv = (p.vt[R0 + r] == 1) ? (p.true_w[d] + p.true_b[d])
                                       : (p.false_w[d] + p.false_b[d]);
        f16 hh = (f16)hv;
        hHi[r * MROW + d] = hh;
        hLo[r * MROW + d] = (f16)(hv - (float)hh);
    }
    __syncthreads();

    for (int rd = 0; rd < NROUNDS; ++rd) {
        // S1: cm MLP on own rows -> t1a
        layerM(hHi, hLo, p.wm_hi + 0 * 16384, p.wm_lo + 0 * 16384, p.cm_b1, true,  aHi, aLo, nullptr, 0);
        layerM(aHi, aLo, p.wm_hi + 1 * 16384, p.wm_lo + 1 * 16384, p.cm_b2, true,  bHi, bLo, nullptr, 0);
        layerM(bHi, bLo, p.wm_hi + 2 * 16384, p.wm_lo + 2 * 16384, p.cm_b3, false, nullptr, nullptr, p.t1a, R0);
        gsync(p.bar, ++ep * NB);
        // S2 (node blocks): gather children + vu LSTM + pm MLP -> t1b
        if (isNode) {
            gatherP(p.t1a, p.ncnt, p.nidx, aHi, aLo, R0);
            gatesL(aHi, aLo, hHi, hLo, cR, p.vu_hi, p.vu_lo, p.vu_bih, p.vu_bhh);
            layerM(hHi, hLo, p.wm_hi + 3 * 16384, p.wm_lo + 3 * 16384, p.pm_b1, true,  aHi, aLo, nullptr, 0);
            layerM(aHi, aLo, p.wm_hi + 4 * 16384, p.wm_lo + 4 * 16384, p.pm_b2, true,  bHi, bLo, nullptr, 0);
            layerM(bHi, bLo, p.wm_hi + 5 * 16384, p.wm_lo + 5 * 16384, p.pm_b3, false, nullptr, nullptr, p.t1b, R0);
        }
        gsync(p.bar, ++ep * NB);
        // S3 (all): gather parents + nu LSTM
        gatherP(p.t1b, p.vcnt, p.vidx, aHi, aLo, R0);
        gatesL(aHi, aLo, hHi, hLo, cR, p.nu_hi, p.nu_lo, p.nu_bih, p.nu_bhh);
    }

    // vote on leaf blocks
    if (!isNode) {
        layerM(hHi, hLo, p.wm_hi + 6 * 16384, p.wm_lo + 6 * 16384, p.vv_b1, true, aHi, aLo, nullptr, 0);
        layerM(aHi, aLo, p.wm_hi + 7 * 16384, p.wm_lo + 7 * 16384, p.vv_b2, true, bHi, bLo, nullptr, 0);
        if (threadIdx.x < 192) {
            int r = threadIdx.x >> 2, q = threadIdx.x & 3;
            float s = 0.f;
#pragma unroll
            for (int u = 0; u < 32; ++u) {
                int col = q * 32 + u;
                s += ((float)bHi[r * MROW + col] + (float)bLo[r * MROW + col]) * p.vv_w3[col];
            }
            s += __shfl_xor(s, 1);
            s += __shfl_xor(s, 2);
            if (q == 0) p.out[R0 - NNODES + r] = s + p.vv_b3[0];
        }
    }
}

// ---------------------------------------------------------------------------
extern "C" void kernel_launch(void* const* d_in, const int* in_sizes, int n_in,
                              void* d_out, int out_size, void* d_ws, size_t ws_size,
                              hipStream_t stream) {
    Params p;
    p.vt      = (const int*)d_in[0];
    p.unpack  = (const unsigned int*)d_in[1];
    p.true_w  = (const float*)d_in[2];
    p.true_b  = (const float*)d_in[3];
    p.false_w = (const float*)d_in[4];
    p.false_b = (const float*)d_in[5];
    p.wsrc[0] = (const float*)d_in[6];  p.cm_b1 = (const float*)d_in[7];
    p.wsrc[1] = (const float*)d_in[8];  p.cm_b2 = (const float*)d_in[9];
    p.wsrc[2] = (const float*)d_in[10]; p.cm_b3 = (const float*)d_in[11];
    p.wsrc[3] = (const float*)d_in[12]; p.pm_b1 = (const float*)d_in[13];
    p.wsrc[4] = (const float*)d_in[14]; p.pm_b2 = (const float*)d_in[15];
    p.wsrc[5] = (const float*)d_in[16]; p.pm_b3 = (const float*)d_in[17];
    p.wsrc[6] = (const float*)d_in[18]; p.vv_b1 = (const float*)d_in[19];
    p.wsrc[7] = (const float*)d_in[20]; p.vv_b2 = (const float*)d_in[21];
    p.vv_w3 = (const float*)d_in[22];   p.vv_b3 = (const float*)d_in[23];
    p.vu_wih = (const float*)d_in[24];  p.vu_whh = (const float*)d_in[25];
    p.vu_bih = (const float*)d_in[26];  p.vu_bhh = (const float*)d_in[27];
    p.nu_wih = (const float*)d_in[28];  p.nu_whh = (const float*)d_in[29];
    p.nu_bih = (const float*)d_in[30];  p.nu_bhh = (const float*)d_in[31];

    float* t1a = (float*)d_ws;                   // [12000][128]
    float* t1b = t1a + (size_t)NVARS * 128;
    int* ncnt = (int*)(t1b + (size_t)NVARS * 128);
    int* nidx = ncnt + NNODES;                   // [NNODES][CAP]
    int* vcnt = nidx + NNODES * CAP;
    int* vidx = vcnt + NVARS;                    // [NVARS][CAP]
    int* bar  = vidx + NVARS * CAP;              // 8*BSLOT ints
    uintptr_t wb = (uintptr_t)(bar + 8 * BSLOT);
    wb = (wb + 15) & ~(uintptr_t)15;
    f16* wm_hi = (f16*)wb;            // 8*16384
    f16* wm_lo = wm_hi + 131072;
    f16* vu_hi = wm_lo + 131072;      // 512*256
    f16* vu_lo = vu_hi + 131072;
    f16* nu_hi = vu_lo + 131072;
    f16* nu_lo = nu_hi + 131072;

    p.t1a = t1a; p.t1b = t1b; p.bar = bar;
    p.ncnt = ncnt; p.nidx = nidx; p.vcnt = vcnt; p.vidx = vidx;
    p.wm_hi = wm_hi; p.wm_lo = wm_lo;
    p.vu_hi = vu_hi; p.vu_lo = vu_lo; p.nu_hi = nu_hi; p.nu_lo = nu_lo;
    p.out = (float*)d_out;

    (void)hipMemsetAsync(ncnt, 0, NNODES * sizeof(int), stream);
    (void)hipMemsetAsync(vcnt, 0, NVARS * sizeof(int), stream);
    (void)hipMemsetAsync(bar, 0, 8 * BSLOT * sizeof(int), stream);
    mega<<<NB, TPB, 0, stream>>>(p);
}